// Round 1
// baseline (214.365 us; speedup 1.0000x reference)
//
#include <hip/hip_runtime.h>
#include <hip/hip_bf16.h>

// KAN layer = GEMM: out[b,o] = sum_{i,k} T_k(tanh(x[b,i])) * W[o,i,k] + bias[o]
// FUSED: the basis matrix A [4096, 8192] bf16 is never materialized.
// Each GEMM block computes its 64x64 A-tile from x on the fly (tanh+Chebyshev
// is ~46 VALU ops/thread/K-step, hidden inside the loop's barrier-drain stalls).
//   B (weights): [1024, 8192] bf16 (converted in ws by conv_kernel) -> gemm_bt
#define MD 4096
#define ND 1024
#define KD 8192
#define IN_F 1024

typedef __bf16 bf16x8 __attribute__((ext_vector_type(8)));
typedef float f32x4 __attribute__((ext_vector_type(4)));

// ---------------- Pass 1: W fp32 -> bf16 (48 MB traffic, ~10 us) ----------
#define N_CONV ((ND * KD) / 8)

__global__ __launch_bounds__(256) void conv_kernel(
    const float* __restrict__ w, __bf16* __restrict__ B) {
  int j = blockIdx.x * blockDim.x + threadIdx.x;  // grid is exact, no tail
  const float4* p = (const float4*)(w + (size_t)j * 8);
  float4 a = p[0], b = p[1];
  bf16x8 v;
  v[0] = (__bf16)a.x; v[1] = (__bf16)a.y; v[2] = (__bf16)a.z; v[3] = (__bf16)a.w;
  v[4] = (__bf16)b.x; v[5] = (__bf16)b.y; v[6] = (__bf16)b.z; v[7] = (__bf16)b.w;
  *(bf16x8*)(B + (size_t)j * 8) = v;
}

// ---------------- Pass 2: fused basis + GEMM_BT + bias ----------------
// BM=64, BN=128, BK=64; 256 threads = 4 waves (2x2), wave tile 32x64 (2x4 of 16x16).
// LDS XOR swizzle: logical 16B group g of row r lives at physical group g^(r&7).
//  - B staged via global_load_lds (swizzle applied on the GLOBAL address side).
//  - A computed in registers, ds_write_b128 directly at swizzled offsets.
#define BM 64
#define BN 128
#define BK 64

__device__ __forceinline__ bf16x8 cheb8(float xs) {
  // fast tanh: copysign(1 - 2/(exp2(2*log2(e)*|x|) + 1), x)
  // |err| ~1e-7 absolute, far below bf16 rounding (4e-3 rel); inf-safe.
  float ax = __builtin_fabsf(xs);
  float e = __builtin_amdgcn_exp2f(ax * 2.88539008177792681472f);
  float r = __builtin_amdgcn_rcpf(e + 1.0f);
  float t = 1.0f - 2.0f * r;
  t = __builtin_copysignf(t, xs);
  float two_t = 2.0f * t;
  float T0 = 1.0f;
  float T1 = t;
  float T2 = two_t * T1 - T0;
  float T3 = two_t * T2 - T1;
  float T4 = two_t * T3 - T2;
  float T5 = two_t * T4 - T3;
  float T6 = two_t * T5 - T4;
  float T7 = two_t * T6 - T5;
  bf16x8 v;
  v[0] = (__bf16)T0; v[1] = (__bf16)T1; v[2] = (__bf16)T2; v[3] = (__bf16)T3;
  v[4] = (__bf16)T4; v[5] = (__bf16)T5; v[6] = (__bf16)T6; v[7] = (__bf16)T7;
  return v;
}

__global__ __launch_bounds__(256) void gemm_bias(
    const float* __restrict__ x, const __bf16* __restrict__ B,
    const float* __restrict__ bias, float* __restrict__ C) {
  __shared__ __align__(16) __bf16 As[BM * BK];
  __shared__ __align__(16) __bf16 Bs[BN * BK];

  const int tid = threadIdx.x;
  const int wave = tid >> 6;
  const int lane = tid & 63;
  const int n0 = blockIdx.x * BN;
  const int m0 = blockIdx.y * BM;
  const int wm = wave >> 1;   // 0..1
  const int wn = wave & 1;    // 0..1

  // ---- B staging: one global_load_lds (16B/lane) covers 8 rows of 128B.
  // lane -> row ar = lane>>3 (r&7 == ar), physical group pg = lane&7.
  // Physical slot (r,pg) must hold logical group pg^ar -> load that column.
  const int ar = lane >> 3;                  // 0..7
  const int swz_col = ((lane & 7) ^ ar) * 8; // swizzled 8-elem column group
  const __bf16* gB = B + (size_t)(n0 + wave * 32 + ar) * KD + swz_col;
  const __bf16* lB = Bs + (wave * 32) * BK;

  // ---- A (basis) staging coords: thread t -> row br = t>>2, groups bg0, bg0+1.
  // K-step kt covers input features ib = kt/8 .. ib+7; logical group g holds
  // T_0..T_7(tanh(x[m0+br, ib+g])). Swizzled dest group = g ^ (br&7).
  const int br = tid >> 2;          // 0..63
  const int bg0 = (tid & 3) * 2;    // 0,2,4,6
  const float* xrow = x + (size_t)(m0 + br) * IN_F + bg0;
  const int sw = br & 7;
  __bf16* aw0 = As + br * BK + ((bg0 ^ sw) * 8);
  __bf16* aw1 = As + br * BK + (((bg0 + 1) ^ sw) * 8);

  f32x4 acc[2][4];
#pragma unroll
  for (int i = 0; i < 2; i++)
#pragma unroll
    for (int j = 0; j < 4; j++) acc[i][j] = (f32x4){0.f, 0.f, 0.f, 0.f};

  // ---- fragment coords (16x16x32: m=lane&15, k=(lane>>4)*8+j)
  const int fr = lane & 15;
  const int fr7 = fr & 7;
  const int qk = lane >> 4;  // 0..3

  // x for kt=0 loaded ahead; each iteration prefetches the next step's x
  // before the barrier so the basis compute never waits on memory.
  float2 xv = *(const float2*)(xrow);

  for (int kt = 0; kt < KD; kt += BK) {
#pragma unroll
    for (int j = 0; j < 4; j++)
      __builtin_amdgcn_global_load_lds(
          (const __attribute__((address_space(1))) void*)(gB + kt + (size_t)j * 8 * KD),
          (__attribute__((address_space(3))) void*)(lB + j * 8 * BK), 16, 0, 0);

    // basis for this K-step (x already in registers)
    bf16x8 v0 = cheb8(xv.x);
    bf16x8 v1 = cheb8(xv.y);
    *(bf16x8*)aw0 = v0;
    *(bf16x8*)aw1 = v1;

    if (kt + BK < KD) xv = *(const float2*)(xrow + ((kt + BK) >> 3));

    __syncthreads();

#pragma unroll
    for (int s = 0; s < 2; s++) {
      // logical 16B group gl = s*4 + qk; physical = gl ^ (row&7) = gl ^ fr7
      const int pa = ((s * 4 + qk) ^ fr7) * 8;
      bf16x8 af[2], bfr[4];
#pragma unroll
      for (int mi = 0; mi < 2; mi++)
        af[mi] = *(const bf16x8*)&As[(wm * 32 + mi * 16 + fr) * BK + pa];
#pragma unroll
      for (int ni = 0; ni < 4; ni++)
        bfr[ni] = *(const bf16x8*)&Bs[(wn * 64 + ni * 16 + fr) * BK + pa];
#pragma unroll
      for (int mi = 0; mi < 2; mi++)
#pragma unroll
        for (int ni = 0; ni < 4; ni++)
          acc[mi][ni] = __builtin_amdgcn_mfma_f32_16x16x32_bf16(
              af[mi], bfr[ni], acc[mi][ni], 0, 0, 0);
    }
    __syncthreads();
  }

  // ---- epilogue: C/D layout col=lane&15, row=(lane>>4)*4+r ; add bias
  const int col0 = n0 + wn * 64;
  const int row0 = m0 + wm * 32 + (lane >> 4) * 4;
#pragma unroll
  for (int ni = 0; ni < 4; ni++) {
    int col = col0 + ni * 16 + (lane & 15);
    float bv = bias[col];
#pragma unroll
    for (int mi = 0; mi < 2; mi++) {
      int row = row0 + mi * 16;
#pragma unroll
      for (int r = 0; r < 4; r++)
        C[(size_t)(row + r) * ND + col] = acc[mi][ni][r] + bv;
    }
  }
}

extern "C" void kernel_launch(void* const* d_in, const int* in_sizes, int n_in,
                              void* d_out, int out_size, void* d_ws, size_t ws_size,
                              hipStream_t stream) {
  const float* x = (const float*)d_in[0];     // [4096,1024]
  const float* w = (const float*)d_in[1];     // [1024,1024,8]
  const float* bias = (const float*)d_in[2];  // [1024]
  float* out = (float*)d_out;                 // [4096,1024]

  __bf16* Bbf = (__bf16*)d_ws;  // 1024*8192 bf16 = 16 MB

  conv_kernel<<<N_CONV / 256, 256, 0, stream>>>(w, Bbf);

  dim3 grid(ND / BN, MD / BM);  // (8, 64) = 512 blocks -> 2 blocks/CU
  gemm_bias<<<grid, 256, 0, stream>>>(x, Bbf, bias, out);
}